// Round 9
// baseline (254.327 us; speedup 1.0000x reference)
//
#include <hip/hip_runtime.h>

#define N_NODES 100000
#define N_EDGES 3200000
#define CH 256

#define GRID_QK 1563     // 64 nodes/block
#define GRID_EX 3125     // 4 edges/thread * 256 thr, exact cover
#define GRID_POOL 512
#define YCOPY 16

// segmented-sum geometry: 4 node-ranges x 64 edge-slices, XCD-cohort swizzled
#define NR 4
#define RANGE 25000      // nodes per range; LDS acc = 100000 B dynamic -> 1 block/CU
#define SL 64            // edge slices
#define EPS 50000        // edges per slice = N_EDGES / SL (exact)
#define QEPS 12500       // EPS/4 int4/float4 loads per slice
#define GP 391           // ceil(N_NODES/256) fold blocks -> ptot entries

#define LDSA_BYTES (RANGE * 4)   // 100,000 B dynamic LDS for k_acc

// ---- ws layout (float offsets) ----
#define OFF_TOTAL 0
#define OFF_PTOT  16        // 512 (only GP used)
#define OFF_YU16  528       // 4096
#define OFF_Q     4624      // 100000
#define OFF_K     104624    // 100000
#define OFF_AWU   204624    // 100000
#define OFF_EX    304624    // 3,200,000 floats (12.8 MB)
#define OFF_PART  3504624   // NR*SL*RANGE = 6,400,000 floats (25.6 MB)
// end = 9,904,624 floats ~= 39.6 MiB (ws ~= 400 MB per fill counters)

// q[n]=x[n,:].Wq+bq, k[n]=x[n,:].Wk+bk. 16-lane dot groups, 4 shuffle levels.
__global__ __launch_bounds__(256) void k_qk(const float* __restrict__ x,
                                            const float* __restrict__ Wq,
                                            const float* __restrict__ bq,
                                            const float* __restrict__ Wk,
                                            const float* __restrict__ bk,
                                            float* __restrict__ q,
                                            float* __restrict__ k,
                                            float* __restrict__ yu16) {
    int t = threadIdx.x;
    if (blockIdx.x < 16) yu16[blockIdx.x * 256 + t] = 0.0f;  // zero for k_pool atomics
    int w = t >> 6, lane = t & 63;
    int g = lane >> 4, seg = lane & 15;
    float4 wq4[4], wk4[4];
    #pragma unroll
    for (int j = 0; j < 4; ++j) {
        wq4[j] = ((const float4*)Wq)[seg + 16 * j];
        wk4[j] = ((const float4*)Wk)[seg + 16 * j];
    }
    float bqs = bq[0], bks = bk[0];
    int base = blockIdx.x * 64 + w * 16 + g;
    #pragma unroll
    for (int i = 0; i < 4; ++i) {
        int n = base + i * 4;
        if (n < N_NODES) {
            const float4* xr = (const float4*)(x + (size_t)n * CH);
            float dq = 0.0f, dk = 0.0f;
            #pragma unroll
            for (int j = 0; j < 4; ++j) {
                float4 xv = xr[seg + 16 * j];
                dq = fmaf(xv.x, wq4[j].x, fmaf(xv.y, wq4[j].y,
                     fmaf(xv.z, wq4[j].z, fmaf(xv.w, wq4[j].w, dq))));
                dk = fmaf(xv.x, wk4[j].x, fmaf(xv.y, wk4[j].y,
                     fmaf(xv.z, wk4[j].z, fmaf(xv.w, wk4[j].w, dk))));
            }
            dq += __shfl_down(dq, 8); dq += __shfl_down(dq, 4);
            dq += __shfl_down(dq, 2); dq += __shfl_down(dq, 1);
            dk += __shfl_down(dk, 8); dk += __shfl_down(dk, 4);
            dk += __shfl_down(dk, 2); dk += __shfl_down(dk, 1);
            if (seg == 0) { q[n] = dq + bqs; k[n] = dk + bks; }
        }
    }
}

// Dense per-edge compute, every edge exactly once: coalesced int4 rows+cols,
// 8 independent gathers (q/k L2-resident, full lane efficiency), leaky+exp,
// coalesced float4 write of ex[].
__global__ __launch_bounds__(256) void k_ex(const int* __restrict__ ei,
                                            const float* __restrict__ q,
                                            const float* __restrict__ k,
                                            float* __restrict__ ex) {
    int i0 = (blockIdx.x * 256 + threadIdx.x) * 4;       // exact: 3125*256*4 == N_EDGES
    const int4 r4 = *(const int4*)(ei + i0);
    const int4 c4 = *(const int4*)(ei + N_EDGES + i0);
    float q0 = q[r4.x], q1 = q[r4.y], q2 = q[r4.z], q3 = q[r4.w];
    float k0 = k[c4.x], k1 = k[c4.y], k2 = k[c4.z], k3 = k[c4.w];
    float v0 = q0 * k0, v1 = q1 * k1, v2 = q2 * k2, v3 = q3 * k3;
    float4 e;
    e.x = __expf(fmaxf(v0, 0.2f * v0));
    e.y = __expf(fmaxf(v1, 0.2f * v1));
    e.z = __expf(fmaxf(v2, 0.2f * v2));
    e.w = __expf(fmaxf(v3, 0.2f * v3));
    *(float4*)(ex + i0) = e;
}

// Slim segmented scatter, NR=4: block (slice s, range r) streams slice rows
// (int4) + precomputed ex (float4); in-range -> ds_add into a 100KB dynamic-LDS
// accumulator; writes one dense partial slab. Rescan L2-fill traffic = 4x25.6MB
// (half of R8's NR=8). Per-XCD footprint = 8 slices x (rows+ex) = 3.2MB (no q/k).
// Swizzle keeps a slice's 4 range-blocks on one XCD; perf-only, any bijection ok.
__global__ __launch_bounds__(1024) void k_acc(const int* __restrict__ ei,
                                              const float* __restrict__ ex,
                                              float* __restrict__ partial) {
    extern __shared__ float acc[];   // RANGE floats = 100,000 B
    int t = threadIdx.x;
    int xcd = blockIdx.x & 7;
    int inner = blockIdx.x >> 3;        // 0..31
    int r = inner & 3;                  // range 0..3
    int s = (inner >> 2) * 8 + xcd;     // slice 0..63; s%8 == xcd
    for (int i = t; i < RANGE; i += 1024) acc[i] = 0.0f;
    __syncthreads();
    int r0 = r * RANGE;
    const int4* r4p = (const int4*)ei + s * QEPS;
    const float4* e4p = (const float4*)ex + s * QEPS;
    for (int i4 = t; i4 < QEPS; i4 += 1024) {
        int4 rv = r4p[i4];
        float4 ev = e4p[i4];
        unsigned o0 = (unsigned)(rv.x - r0);
        unsigned o1 = (unsigned)(rv.y - r0);
        unsigned o2 = (unsigned)(rv.z - r0);
        unsigned o3 = (unsigned)(rv.w - r0);
        if (o0 < RANGE) atomicAdd(&acc[o0], ev.x);   // ds_add_f32
        if (o1 < RANGE) atomicAdd(&acc[o1], ev.y);
        if (o2 < RANGE) atomicAdd(&acc[o2], ev.z);
        if (o3 < RANGE) atomicAdd(&acc[o3], ev.w);
    }
    __syncthreads();
    float* dst = partial + ((size_t)r * SL + s) * RANGE;
    for (int i = t; i < RANGE; i += 1024) dst[i] = acc[i];
}

// Stage 2: awu[n] = sum_s partial[range(n)][s][n%RANGE]; ptot[blk] = block total partial
__global__ __launch_bounds__(256) void k_fold(const float* __restrict__ partial,
                                              float* __restrict__ awu,
                                              float* __restrict__ ptot) {
    int t = threadIdx.x;
    int n = blockIdx.x * 256 + t;
    float s = 0.0f;
    if (n < N_NODES) {
        int r = n / RANGE, off = n % RANGE;   // magic-mul div
        const float* p = partial + (size_t)r * SL * RANGE + off;
        #pragma unroll 8
        for (int g = 0; g < SL; ++g) s += p[(size_t)g * RANGE];
        awu[n] = s;
    }
    float rsum = s;
    #pragma unroll
    for (int off = 32; off; off >>= 1) rsum += __shfl_down(rsum, off);
    __shared__ float sm[4];
    if ((t & 63) == 0) sm[t >> 6] = rsum;
    __syncthreads();
    if (t == 0) ptot[blockIdx.x] = sm[0] + sm[1] + sm[2] + sm[3];
}

// total inline from ptot; yu16 atomic partials; aw_out = awu/total
__global__ __launch_bounds__(256) void k_pool(const float* __restrict__ x,
                                              const float* __restrict__ awu,
                                              const float* __restrict__ ptot,
                                              float* __restrict__ totalp,
                                              float* __restrict__ yu16,
                                              float* __restrict__ aw_out) {
    int t = threadIdx.x, s = t >> 6, g = t & 63;
    // reduce ptot[0..GP) -> total (every block, cheap)
    float ts = ptot[t] + ((t + 256 < GP) ? ptot[t + 256] : 0.0f);
    #pragma unroll
    for (int off = 32; off; off >>= 1) ts += __shfl_down(ts, off);
    __shared__ float sm[4];
    __shared__ float tot;
    if (g == 0) sm[s] = ts;
    __syncthreads();
    if (t == 0) {
        tot = sm[0] + sm[1] + sm[2] + sm[3];
        if (blockIdx.x == 0) totalp[0] = tot;
    }
    __syncthreads();
    float inv = 1.0f / tot;

    const float4* X4 = (const float4*)x;
    float4 acc = make_float4(0.f, 0.f, 0.f, 0.f);
    for (int base = blockIdx.x * 8; base < N_NODES; base += GRID_POOL * 8) {
        float a0 = awu[base + s];
        float a1 = awu[base + 4 + s];
        float4 x0 = X4[(size_t)(base + s) * 64 + g];
        float4 x1 = X4[(size_t)(base + 4 + s) * 64 + g];
        acc.x = fmaf(a0, x0.x, acc.x); acc.y = fmaf(a0, x0.y, acc.y);
        acc.z = fmaf(a0, x0.z, acc.z); acc.w = fmaf(a0, x0.w, acc.w);
        acc.x = fmaf(a1, x1.x, acc.x); acc.y = fmaf(a1, x1.y, acc.y);
        acc.z = fmaf(a1, x1.z, acc.z); acc.w = fmaf(a1, x1.w, acc.w);
    }
    __shared__ float4 tmp4[4][64];
    tmp4[s][g] = acc;
    __syncthreads();
    const float* tmp = (const float*)tmp4;
    float sum = tmp[0 * 256 + t] + tmp[1 * 256 + t] + tmp[2 * 256 + t] + tmp[3 * 256 + t];
    atomicAdd(&yu16[(blockIdx.x & (YCOPY - 1)) * 256 + t], sum);
    for (int i = blockIdx.x * 256 + t; i < N_NODES; i += GRID_POOL * 256)
        aw_out[i] = awu[i] * inv;
}

// grid 8: block j -> out[j*32 .. j*32+32)
__global__ __launch_bounds__(256) void k_final(const float* __restrict__ yu16,
                                               const float* __restrict__ totalp,
                                               const float* __restrict__ Wv,
                                               const float* __restrict__ bv,
                                               float* __restrict__ out) {
    __shared__ float ysh[256];
    __shared__ float red[256];
    int t = threadIdx.x;
    float inv = 1.0f / totalp[0];
    float yv = 0.0f;
    #pragma unroll
    for (int j = 0; j < YCOPY; ++j) yv += yu16[j * 256 + t];
    ysh[t] = yv * inv;
    __syncthreads();
    int c = blockIdx.x * 32 + (t & 31), rg = t >> 5;
    float acc = 0.0f;
    #pragma unroll
    for (int j = 0; j < 32; ++j) {
        int kk = rg * 32 + j;
        acc = fmaf(ysh[kk], Wv[(size_t)kk * CH + c], acc);
    }
    red[t] = acc;
    __syncthreads();
    if (t < 32) {
        float sv = 0.0f;
        #pragma unroll
        for (int j = 0; j < 8; ++j) sv += red[j * 32 + t];
        out[blockIdx.x * 32 + t] = sv + bv[blockIdx.x * 32 + t];
    }
}

extern "C" void kernel_launch(void* const* d_in, const int* in_sizes, int n_in,
                              void* d_out, int out_size, void* d_ws, size_t ws_size,
                              hipStream_t stream) {
    const float* x  = (const float*)d_in[0];
    const int*   ei = (const int*)d_in[1];
    const float* Wq = (const float*)d_in[2];
    const float* bq = (const float*)d_in[3];
    const float* Wk = (const float*)d_in[4];
    const float* bk = (const float*)d_in[5];
    const float* Wv = (const float*)d_in[6];
    const float* bv = (const float*)d_in[7];
    float* out = (float*)d_out;
    float* ws  = (float*)d_ws;

    float* totalp  = ws + OFF_TOTAL;
    float* ptot    = ws + OFF_PTOT;
    float* yu16    = ws + OFF_YU16;
    float* q       = ws + OFF_Q;
    float* k       = ws + OFF_K;
    float* awu     = ws + OFF_AWU;
    float* ex      = ws + OFF_EX;
    float* partial = ws + OFF_PART;

    // one-time host-side attribute: allow 100 KB dynamic LDS (not a stream op)
    static bool lds_init = false;
    if (!lds_init) {
        (void)hipFuncSetAttribute((const void*)k_acc,
                                  hipFuncAttributeMaxDynamicSharedMemorySize,
                                  LDSA_BYTES);
        lds_init = true;
    }

    hipLaunchKernelGGL(k_qk, dim3(GRID_QK), dim3(256), 0, stream,
                       x, Wq, bq, Wk, bk, q, k, yu16);
    hipLaunchKernelGGL(k_ex, dim3(GRID_EX), dim3(256), 0, stream,
                       ei, q, k, ex);
    hipLaunchKernelGGL(k_acc, dim3(NR * SL), dim3(1024), LDSA_BYTES, stream,
                       ei, ex, partial);
    hipLaunchKernelGGL(k_fold, dim3(GP), dim3(256), 0, stream,
                       partial, awu, ptot);
    hipLaunchKernelGGL(k_pool, dim3(GRID_POOL), dim3(256), 0, stream,
                       x, awu, ptot, totalp, yu16, out + CH);
    hipLaunchKernelGGL(k_final, dim3(8), dim3(256), 0, stream,
                       yu16, totalp, Wv, bv, out);
}

// Round 10
// 241.086 us; speedup vs baseline: 1.0549x; 1.0549x over previous
//
#include <hip/hip_runtime.h>

#define N_NODES 100000
#define N_EDGES 3200000
#define CH 256

#define GRID_QK 1563     // 64 nodes/block
#define GRID_POOL 512
#define YCOPY 16

// segmented-sum geometry: 8 node-ranges x 64 edge-slices, XCD-cohort swizzled
#define NR 8
#define RANGE 12500      // nodes per range; LDS acc = 50 KB static -> 2 blocks/CU
#define SL 64            // edge slices
#define EPS 50000        // edges per slice = N_EDGES / SL (exact)
#define QEPS 12500       // EPS/4 int4 loads per slice
#define GP 391           // ceil(N_NODES/256) fold blocks -> ptot entries

// ---- ws layout (float offsets) ----
#define OFF_TOTAL 0
#define OFF_PTOT  16       // 512 (only GP used)
#define OFF_YU16  528      // 4096
#define OFF_Q     4624     // 100000
#define OFF_K     104624   // 100000
#define OFF_AWU   204624   // 100000
#define OFF_PART  304624   // NR*SL*RANGE = 6,400,000 floats (25.6 MB)
// end = 6,704,624 floats ~= 26.8 MiB

// q[n]=x[n,:].Wq+bq, k[n]=x[n,:].Wk+bk. 16-lane dot groups, 4 shuffle levels.
__global__ __launch_bounds__(256) void k_qk(const float* __restrict__ x,
                                            const float* __restrict__ Wq,
                                            const float* __restrict__ bq,
                                            const float* __restrict__ Wk,
                                            const float* __restrict__ bk,
                                            float* __restrict__ q,
                                            float* __restrict__ k,
                                            float* __restrict__ yu16) {
    int t = threadIdx.x;
    if (blockIdx.x < 16) yu16[blockIdx.x * 256 + t] = 0.0f;  // zero for k_pool atomics
    int w = t >> 6, lane = t & 63;
    int g = lane >> 4, seg = lane & 15;
    float4 wq4[4], wk4[4];
    #pragma unroll
    for (int j = 0; j < 4; ++j) {
        wq4[j] = ((const float4*)Wq)[seg + 16 * j];
        wk4[j] = ((const float4*)Wk)[seg + 16 * j];
    }
    float bqs = bq[0], bks = bk[0];
    int base = blockIdx.x * 64 + w * 16 + g;
    #pragma unroll
    for (int i = 0; i < 4; ++i) {
        int n = base + i * 4;
        if (n < N_NODES) {
            const float4* xr = (const float4*)(x + (size_t)n * CH);
            float dq = 0.0f, dk = 0.0f;
            #pragma unroll
            for (int j = 0; j < 4; ++j) {
                float4 xv = xr[seg + 16 * j];
                dq = fmaf(xv.x, wq4[j].x, fmaf(xv.y, wq4[j].y,
                     fmaf(xv.z, wq4[j].z, fmaf(xv.w, wq4[j].w, dq))));
                dk = fmaf(xv.x, wk4[j].x, fmaf(xv.y, wk4[j].y,
                     fmaf(xv.z, wk4[j].z, fmaf(xv.w, wk4[j].w, dk))));
            }
            dq += __shfl_down(dq, 8); dq += __shfl_down(dq, 4);
            dq += __shfl_down(dq, 2); dq += __shfl_down(dq, 1);
            dk += __shfl_down(dk, 8); dk += __shfl_down(dk, 4);
            dk += __shfl_down(dk, 2); dk += __shfl_down(dk, 1);
            if (seg == 0) { q[n] = dq + bqs; k[n] = dk + bks; }
        }
    }
}

// Segmented sum, stage 1 (R7 base + MLP widening). Block (slice s, range r):
// processes TWO int4 bundles per loop iteration (stride 2048) so 4 index loads
// + up to 8 predicated gathers are in flight per latency step -> halves the
// per-thread count of serialized dependent-load chains (the ~51us invariant).
// XCD-cohort swizzle keeps a slice's 8 range-blocks on one XCD L2 (perf-only).
__global__ __launch_bounds__(1024) void k_acc(const int* __restrict__ ei,
                                              const float* __restrict__ q,
                                              const float* __restrict__ k,
                                              float* __restrict__ partial) {
    __shared__ float acc[RANGE];   // 50,000 B static LDS -> 2 blocks/CU
    int t = threadIdx.x;
    int xcd = blockIdx.x & 7;
    int inner = blockIdx.x >> 3;        // 0..63
    int r = inner & 7;                  // range 0..7
    int s = (inner >> 3) * 8 + xcd;     // slice 0..63; s%8 == xcd
    for (int i = t; i < RANGE; i += 1024) acc[i] = 0.0f;
    __syncthreads();
    int r0 = r * RANGE;
    const int4* r4p = (const int4*)ei + s * QEPS;
    const int4* c4p = (const int4*)(ei + N_EDGES) + s * QEPS;
    for (int i4 = t; i4 < QEPS; i4 += 2048) {
        // bundle A + bundle B index loads issue together (4x16B in flight)
        int4 rvA = r4p[i4];
        int4 cvA = c4p[i4];
        int j4 = i4 + 1024;
        bool hasB = (j4 < QEPS);
        int4 rvB, cvB;
        if (hasB) { rvB = r4p[j4]; cvB = c4p[j4]; }
        unsigned a0 = (unsigned)(rvA.x - r0);
        unsigned a1 = (unsigned)(rvA.y - r0);
        unsigned a2 = (unsigned)(rvA.z - r0);
        unsigned a3 = (unsigned)(rvA.w - r0);
        if (a0 < RANGE) {
            float v = q[rvA.x] * k[cvA.x];
            atomicAdd(&acc[a0], __expf(fmaxf(v, 0.2f * v)));   // ds_add_f32
        }
        if (a1 < RANGE) {
            float v = q[rvA.y] * k[cvA.y];
            atomicAdd(&acc[a1], __expf(fmaxf(v, 0.2f * v)));
        }
        if (a2 < RANGE) {
            float v = q[rvA.z] * k[cvA.z];
            atomicAdd(&acc[a2], __expf(fmaxf(v, 0.2f * v)));
        }
        if (a3 < RANGE) {
            float v = q[rvA.w] * k[cvA.w];
            atomicAdd(&acc[a3], __expf(fmaxf(v, 0.2f * v)));
        }
        if (hasB) {
            unsigned b0 = (unsigned)(rvB.x - r0);
            unsigned b1 = (unsigned)(rvB.y - r0);
            unsigned b2 = (unsigned)(rvB.z - r0);
            unsigned b3 = (unsigned)(rvB.w - r0);
            if (b0 < RANGE) {
                float v = q[rvB.x] * k[cvB.x];
                atomicAdd(&acc[b0], __expf(fmaxf(v, 0.2f * v)));
            }
            if (b1 < RANGE) {
                float v = q[rvB.y] * k[cvB.y];
                atomicAdd(&acc[b1], __expf(fmaxf(v, 0.2f * v)));
            }
            if (b2 < RANGE) {
                float v = q[rvB.z] * k[cvB.z];
                atomicAdd(&acc[b2], __expf(fmaxf(v, 0.2f * v)));
            }
            if (b3 < RANGE) {
                float v = q[rvB.w] * k[cvB.w];
                atomicAdd(&acc[b3], __expf(fmaxf(v, 0.2f * v)));
            }
        }
    }
    __syncthreads();
    float* dst = partial + ((size_t)r * SL + s) * RANGE;
    for (int i = t; i < RANGE; i += 1024) dst[i] = acc[i];
}

// Stage 2: awu[n] = sum_s partial[range(n)][s][n%RANGE]; ptot[blk] = block total partial
__global__ __launch_bounds__(256) void k_fold(const float* __restrict__ partial,
                                              float* __restrict__ awu,
                                              float* __restrict__ ptot) {
    int t = threadIdx.x;
    int n = blockIdx.x * 256 + t;
    float s = 0.0f;
    if (n < N_NODES) {
        int r = n / RANGE, off = n % RANGE;   // magic-mul div
        const float* p = partial + (size_t)r * SL * RANGE + off;
        #pragma unroll 8
        for (int g = 0; g < SL; ++g) s += p[(size_t)g * RANGE];
        awu[n] = s;
    }
    float rsum = s;
    #pragma unroll
    for (int off = 32; off; off >>= 1) rsum += __shfl_down(rsum, off);
    __shared__ float sm[4];
    if ((t & 63) == 0) sm[t >> 6] = rsum;
    __syncthreads();
    if (t == 0) ptot[blockIdx.x] = sm[0] + sm[1] + sm[2] + sm[3];
}

// total inline from ptot; yu16 atomic partials; aw_out = awu/total
__global__ __launch_bounds__(256) void k_pool(const float* __restrict__ x,
                                              const float* __restrict__ awu,
                                              const float* __restrict__ ptot,
                                              float* __restrict__ totalp,
                                              float* __restrict__ yu16,
                                              float* __restrict__ aw_out) {
    int t = threadIdx.x, s = t >> 6, g = t & 63;
    // reduce ptot[0..GP) -> total (every block, cheap)
    float ts = ptot[t] + ((t + 256 < GP) ? ptot[t + 256] : 0.0f);
    #pragma unroll
    for (int off = 32; off; off >>= 1) ts += __shfl_down(ts, off);
    __shared__ float sm[4];
    __shared__ float tot;
    if (g == 0) sm[s] = ts;
    __syncthreads();
    if (t == 0) {
        tot = sm[0] + sm[1] + sm[2] + sm[3];
        if (blockIdx.x == 0) totalp[0] = tot;
    }
    __syncthreads();
    float inv = 1.0f / tot;

    const float4* X4 = (const float4*)x;
    float4 acc = make_float4(0.f, 0.f, 0.f, 0.f);
    for (int base = blockIdx.x * 8; base < N_NODES; base += GRID_POOL * 8) {
        float a0 = awu[base + s];
        float a1 = awu[base + 4 + s];
        float4 x0 = X4[(size_t)(base + s) * 64 + g];
        float4 x1 = X4[(size_t)(base + 4 + s) * 64 + g];
        acc.x = fmaf(a0, x0.x, acc.x); acc.y = fmaf(a0, x0.y, acc.y);
        acc.z = fmaf(a0, x0.z, acc.z); acc.w = fmaf(a0, x0.w, acc.w);
        acc.x = fmaf(a1, x1.x, acc.x); acc.y = fmaf(a1, x1.y, acc.y);
        acc.z = fmaf(a1, x1.z, acc.z); acc.w = fmaf(a1, x1.w, acc.w);
    }
    __shared__ float4 tmp4[4][64];
    tmp4[s][g] = acc;
    __syncthreads();
    const float* tmp = (const float*)tmp4;
    float sum = tmp[0 * 256 + t] + tmp[1 * 256 + t] + tmp[2 * 256 + t] + tmp[3 * 256 + t];
    atomicAdd(&yu16[(blockIdx.x & (YCOPY - 1)) * 256 + t], sum);
    for (int i = blockIdx.x * 256 + t; i < N_NODES; i += GRID_POOL * 256)
        aw_out[i] = awu[i] * inv;
}

// grid 8: block j -> out[j*32 .. j*32+32)
__global__ __launch_bounds__(256) void k_final(const float* __restrict__ yu16,
                                               const float* __restrict__ totalp,
                                               const float* __restrict__ Wv,
                                               const float* __restrict__ bv,
                                               float* __restrict__ out) {
    __shared__ float ysh[256];
    __shared__ float red[256];
    int t = threadIdx.x;
    float inv = 1.0f / totalp[0];
    float yv = 0.0f;
    #pragma unroll
    for (int j = 0; j < YCOPY; ++j) yv += yu16[j * 256 + t];
    ysh[t] = yv * inv;
    __syncthreads();
    int c = blockIdx.x * 32 + (t & 31), rg = t >> 5;
    float acc = 0.0f;
    #pragma unroll
    for (int j = 0; j < 32; ++j) {
        int kk = rg * 32 + j;
        acc = fmaf(ysh[kk], Wv[(size_t)kk * CH + c], acc);
    }
    red[t] = acc;
    __syncthreads();
    if (t < 32) {
        float sv = 0.0f;
        #pragma unroll
        for (int j = 0; j < 8; ++j) sv += red[j * 32 + t];
        out[blockIdx.x * 32 + t] = sv + bv[blockIdx.x * 32 + t];
    }
}

extern "C" void kernel_launch(void* const* d_in, const int* in_sizes, int n_in,
                              void* d_out, int out_size, void* d_ws, size_t ws_size,
                              hipStream_t stream) {
    const float* x  = (const float*)d_in[0];
    const int*   ei = (const int*)d_in[1];
    const float* Wq = (const float*)d_in[2];
    const float* bq = (const float*)d_in[3];
    const float* Wk = (const float*)d_in[4];
    const float* bk = (const float*)d_in[5];
    const float* Wv = (const float*)d_in[6];
    const float* bv = (const float*)d_in[7];
    float* out = (float*)d_out;
    float* ws  = (float*)d_ws;

    float* totalp  = ws + OFF_TOTAL;
    float* ptot    = ws + OFF_PTOT;
    float* yu16    = ws + OFF_YU16;
    float* q       = ws + OFF_Q;
    float* k       = ws + OFF_K;
    float* awu     = ws + OFF_AWU;
    float* partial = ws + OFF_PART;

    hipLaunchKernelGGL(k_qk, dim3(GRID_QK), dim3(256), 0, stream,
                       x, Wq, bq, Wk, bk, q, k, yu16);
    hipLaunchKernelGGL(k_acc, dim3(NR * SL), dim3(1024), 0, stream,
                       ei, q, k, partial);
    hipLaunchKernelGGL(k_fold, dim3(GP), dim3(256), 0, stream,
                       partial, awu, ptot);
    hipLaunchKernelGGL(k_pool, dim3(GRID_POOL), dim3(256), 0, stream,
                       x, awu, ptot, totalp, yu16, out + CH);
    hipLaunchKernelGGL(k_final, dim3(8), dim3(256), 0, stream,
                       yu16, totalp, Wv, bv, out);
}

// Round 11
// 237.680 us; speedup vs baseline: 1.0700x; 1.0143x over previous
//
#include <hip/hip_runtime.h>

#define N_NODES 100000
#define N_EDGES 3200000
#define CH 256

#define GRID_QK 1563     // 64 nodes/block
#define GRID_POOL 512
#define YCOPY 16

// segmented-sum geometry: 4 node-ranges x 64 edge-slices, XCD-cohort swizzled
#define NR 4
#define RANGE 25000      // nodes per range; LDS acc = 100000 B dynamic -> 1 block/CU
#define SL 64            // edge slices; grid = NR*SL = 256 = exactly 1 block/CU
#define EPS 50000        // edges per slice = N_EDGES / SL (exact)
#define QEPS 12500       // EPS/4 int4 loads per slice
#define GP 391           // ceil(N_NODES/256) fold blocks -> ptot entries

#define LDSA_BYTES (RANGE * 4)   // 100,000 B dynamic LDS for k_acc

// ---- ws layout (float offsets) ----
#define OFF_TOTAL 0
#define OFF_PTOT  16       // 512 (only GP used)
#define OFF_YU16  528      // 4096
#define OFF_Q     4624     // 100000
#define OFF_K     104624   // 100000
#define OFF_AWU   204624   // 100000
#define OFF_PART  304624   // NR*SL*RANGE = 6,400,000 floats (25.6 MB)
// end = 6,704,624 floats ~= 26.8 MiB

// q[n]=x[n,:].Wq+bq, k[n]=x[n,:].Wk+bk. 16-lane dot groups, 4 shuffle levels.
__global__ __launch_bounds__(256) void k_qk(const float* __restrict__ x,
                                            const float* __restrict__ Wq,
                                            const float* __restrict__ bq,
                                            const float* __restrict__ Wk,
                                            const float* __restrict__ bk,
                                            float* __restrict__ q,
                                            float* __restrict__ k,
                                            float* __restrict__ yu16) {
    int t = threadIdx.x;
    if (blockIdx.x < 16) yu16[blockIdx.x * 256 + t] = 0.0f;  // zero for k_pool atomics
    int w = t >> 6, lane = t & 63;
    int g = lane >> 4, seg = lane & 15;
    float4 wq4[4], wk4[4];
    #pragma unroll
    for (int j = 0; j < 4; ++j) {
        wq4[j] = ((const float4*)Wq)[seg + 16 * j];
        wk4[j] = ((const float4*)Wk)[seg + 16 * j];
    }
    float bqs = bq[0], bks = bk[0];
    int base = blockIdx.x * 64 + w * 16 + g;
    #pragma unroll
    for (int i = 0; i < 4; ++i) {
        int n = base + i * 4;
        if (n < N_NODES) {
            const float4* xr = (const float4*)(x + (size_t)n * CH);
            float dq = 0.0f, dk = 0.0f;
            #pragma unroll
            for (int j = 0; j < 4; ++j) {
                float4 xv = xr[seg + 16 * j];
                dq = fmaf(xv.x, wq4[j].x, fmaf(xv.y, wq4[j].y,
                     fmaf(xv.z, wq4[j].z, fmaf(xv.w, wq4[j].w, dq))));
                dk = fmaf(xv.x, wk4[j].x, fmaf(xv.y, wk4[j].y,
                     fmaf(xv.z, wk4[j].z, fmaf(xv.w, wk4[j].w, dk))));
            }
            dq += __shfl_down(dq, 8); dq += __shfl_down(dq, 4);
            dq += __shfl_down(dq, 2); dq += __shfl_down(dq, 1);
            dk += __shfl_down(dk, 8); dk += __shfl_down(dk, 4);
            dk += __shfl_down(dk, 2); dk += __shfl_down(dk, 1);
            if (seg == 0) { q[n] = dq + bqs; k[n] = dk + bks; }
        }
    }
}

// Segmented sum, stage 1. NR=4 (half of R10's rescan fill traffic) with 4-wide
// MLP: 4 int4 row-bundles + 4 int4 col-bundles issued per latency step, so the
// per-CU in-flight load product (16 waves x 8 loads) matches R10's (32 x 4) --
// the latency-BW model's test: constant in-flight, half traffic => ~half time.
// XCD-cohort swizzle keeps a slice's 4 range-blocks on one XCD L2 (perf-only).
__global__ __launch_bounds__(1024) void k_acc(const int* __restrict__ ei,
                                              const float* __restrict__ q,
                                              const float* __restrict__ k,
                                              float* __restrict__ partial) {
    extern __shared__ float acc[];   // RANGE floats = 100,000 B dynamic LDS
    int t = threadIdx.x;
    int xcd = blockIdx.x & 7;
    int inner = blockIdx.x >> 3;        // 0..31
    int r = inner & 3;                  // range 0..3
    int s = (inner >> 2) * 8 + xcd;     // slice 0..63; s%8 == xcd
    for (int i = t; i < RANGE; i += 1024) acc[i] = 0.0f;
    __syncthreads();
    int r0 = r * RANGE;
    const int4* r4p = (const int4*)ei + s * QEPS;
    const int4* c4p = (const int4*)(ei + N_EDGES) + s * QEPS;
    for (int base = t; base < QEPS; base += 4096) {
        int4 rv0, rv1, rv2, rv3, cv0, cv1, cv2, cv3;
        int i1 = base + 1024, i2 = base + 2048, i3 = base + 3072;
        bool h1 = i1 < QEPS, h2 = i2 < QEPS, h3 = i3 < QEPS;
        // issue all index loads first: up to 8x16B in flight per thread
        rv0 = r4p[base];            cv0 = c4p[base];
        if (h1) { rv1 = r4p[i1];    cv1 = c4p[i1]; }
        if (h2) { rv2 = r4p[i2];    cv2 = c4p[i2]; }
        if (h3) { rv3 = r4p[i3];    cv3 = c4p[i3]; }
        #define DO4(rv, cv)                                                   \
        {                                                                     \
            unsigned o0 = (unsigned)(rv.x - r0);                              \
            unsigned o1 = (unsigned)(rv.y - r0);                              \
            unsigned o2 = (unsigned)(rv.z - r0);                              \
            unsigned o3 = (unsigned)(rv.w - r0);                              \
            if (o0 < RANGE) {                                                 \
                float v = q[rv.x] * k[cv.x];                                  \
                atomicAdd(&acc[o0], __expf(fmaxf(v, 0.2f * v)));              \
            }                                                                 \
            if (o1 < RANGE) {                                                 \
                float v = q[rv.y] * k[cv.y];                                  \
                atomicAdd(&acc[o1], __expf(fmaxf(v, 0.2f * v)));              \
            }                                                                 \
            if (o2 < RANGE) {                                                 \
                float v = q[rv.z] * k[cv.z];                                  \
                atomicAdd(&acc[o2], __expf(fmaxf(v, 0.2f * v)));              \
            }                                                                 \
            if (o3 < RANGE) {                                                 \
                float v = q[rv.w] * k[cv.w];                                  \
                atomicAdd(&acc[o3], __expf(fmaxf(v, 0.2f * v)));              \
            }                                                                 \
        }
        DO4(rv0, cv0);
        if (h1) DO4(rv1, cv1);
        if (h2) DO4(rv2, cv2);
        if (h3) DO4(rv3, cv3);
        #undef DO4
    }
    __syncthreads();
    float* dst = partial + ((size_t)r * SL + s) * RANGE;
    for (int i = t; i < RANGE; i += 1024) dst[i] = acc[i];
}

// Stage 2: awu[n] = sum_s partial[range(n)][s][n%RANGE]; ptot[blk] = block total partial
__global__ __launch_bounds__(256) void k_fold(const float* __restrict__ partial,
                                              float* __restrict__ awu,
                                              float* __restrict__ ptot) {
    int t = threadIdx.x;
    int n = blockIdx.x * 256 + t;
    float s = 0.0f;
    if (n < N_NODES) {
        int r = n / RANGE, off = n % RANGE;   // magic-mul div
        const float* p = partial + (size_t)r * SL * RANGE + off;
        #pragma unroll 8
        for (int g = 0; g < SL; ++g) s += p[(size_t)g * RANGE];
        awu[n] = s;
    }
    float rsum = s;
    #pragma unroll
    for (int off = 32; off; off >>= 1) rsum += __shfl_down(rsum, off);
    __shared__ float sm[4];
    if ((t & 63) == 0) sm[t >> 6] = rsum;
    __syncthreads();
    if (t == 0) ptot[blockIdx.x] = sm[0] + sm[1] + sm[2] + sm[3];
}

// total inline from ptot; yu16 atomic partials; aw_out = awu/total
__global__ __launch_bounds__(256) void k_pool(const float* __restrict__ x,
                                              const float* __restrict__ awu,
                                              const float* __restrict__ ptot,
                                              float* __restrict__ totalp,
                                              float* __restrict__ yu16,
                                              float* __restrict__ aw_out) {
    int t = threadIdx.x, s = t >> 6, g = t & 63;
    // reduce ptot[0..GP) -> total (every block, cheap)
    float ts = ptot[t] + ((t + 256 < GP) ? ptot[t + 256] : 0.0f);
    #pragma unroll
    for (int off = 32; off; off >>= 1) ts += __shfl_down(ts, off);
    __shared__ float sm[4];
    __shared__ float tot;
    if (g == 0) sm[s] = ts;
    __syncthreads();
    if (t == 0) {
        tot = sm[0] + sm[1] + sm[2] + sm[3];
        if (blockIdx.x == 0) totalp[0] = tot;
    }
    __syncthreads();
    float inv = 1.0f / tot;

    const float4* X4 = (const float4*)x;
    float4 acc = make_float4(0.f, 0.f, 0.f, 0.f);
    for (int base = blockIdx.x * 8; base < N_NODES; base += GRID_POOL * 8) {
        float a0 = awu[base + s];
        float a1 = awu[base + 4 + s];
        float4 x0 = X4[(size_t)(base + s) * 64 + g];
        float4 x1 = X4[(size_t)(base + 4 + s) * 64 + g];
        acc.x = fmaf(a0, x0.x, acc.x); acc.y = fmaf(a0, x0.y, acc.y);
        acc.z = fmaf(a0, x0.z, acc.z); acc.w = fmaf(a0, x0.w, acc.w);
        acc.x = fmaf(a1, x1.x, acc.x); acc.y = fmaf(a1, x1.y, acc.y);
        acc.z = fmaf(a1, x1.z, acc.z); acc.w = fmaf(a1, x1.w, acc.w);
    }
    __shared__ float4 tmp4[4][64];
    tmp4[s][g] = acc;
    __syncthreads();
    const float* tmp = (const float*)tmp4;
    float sum = tmp[0 * 256 + t] + tmp[1 * 256 + t] + tmp[2 * 256 + t] + tmp[3 * 256 + t];
    atomicAdd(&yu16[(blockIdx.x & (YCOPY - 1)) * 256 + t], sum);
    for (int i = blockIdx.x * 256 + t; i < N_NODES; i += GRID_POOL * 256)
        aw_out[i] = awu[i] * inv;
}

// grid 8: block j -> out[j*32 .. j*32+32)
__global__ __launch_bounds__(256) void k_final(const float* __restrict__ yu16,
                                               const float* __restrict__ totalp,
                                               const float* __restrict__ Wv,
                                               const float* __restrict__ bv,
                                               float* __restrict__ out) {
    __shared__ float ysh[256];
    __shared__ float red[256];
    int t = threadIdx.x;
    float inv = 1.0f / totalp[0];
    float yv = 0.0f;
    #pragma unroll
    for (int j = 0; j < YCOPY; ++j) yv += yu16[j * 256 + t];
    ysh[t] = yv * inv;
    __syncthreads();
    int c = blockIdx.x * 32 + (t & 31), rg = t >> 5;
    float acc = 0.0f;
    #pragma unroll
    for (int j = 0; j < 32; ++j) {
        int kk = rg * 32 + j;
        acc = fmaf(ysh[kk], Wv[(size_t)kk * CH + c], acc);
    }
    red[t] = acc;
    __syncthreads();
    if (t < 32) {
        float sv = 0.0f;
        #pragma unroll
        for (int j = 0; j < 8; ++j) sv += red[j * 32 + t];
        out[blockIdx.x * 32 + t] = sv + bv[blockIdx.x * 32 + t];
    }
}

extern "C" void kernel_launch(void* const* d_in, const int* in_sizes, int n_in,
                              void* d_out, int out_size, void* d_ws, size_t ws_size,
                              hipStream_t stream) {
    const float* x  = (const float*)d_in[0];
    const int*   ei = (const int*)d_in[1];
    const float* Wq = (const float*)d_in[2];
    const float* bq = (const float*)d_in[3];
    const float* Wk = (const float*)d_in[4];
    const float* bk = (const float*)d_in[5];
    const float* Wv = (const float*)d_in[6];
    const float* bv = (const float*)d_in[7];
    float* out = (float*)d_out;
    float* ws  = (float*)d_ws;

    float* totalp  = ws + OFF_TOTAL;
    float* ptot    = ws + OFF_PTOT;
    float* yu16    = ws + OFF_YU16;
    float* q       = ws + OFF_Q;
    float* k       = ws + OFF_K;
    float* awu     = ws + OFF_AWU;
    float* partial = ws + OFF_PART;

    // one-time host-side attribute: allow 100 KB dynamic LDS (not a stream op)
    static bool lds_init = false;
    if (!lds_init) {
        (void)hipFuncSetAttribute((const void*)k_acc,
                                  hipFuncAttributeMaxDynamicSharedMemorySize,
                                  LDSA_BYTES);
        lds_init = true;
    }

    hipLaunchKernelGGL(k_qk, dim3(GRID_QK), dim3(256), 0, stream,
                       x, Wq, bq, Wk, bk, q, k, yu16);
    hipLaunchKernelGGL(k_acc, dim3(NR * SL), dim3(1024), LDSA_BYTES, stream,
                       ei, q, k, partial);
    hipLaunchKernelGGL(k_fold, dim3(GP), dim3(256), 0, stream,
                       partial, awu, ptot);
    hipLaunchKernelGGL(k_pool, dim3(GRID_POOL), dim3(256), 0, stream,
                       x, awu, ptot, totalp, yu16, out + CH);
    hipLaunchKernelGGL(k_final, dim3(8), dim3(256), 0, stream,
                       yu16, totalp, Wv, bv, out);
}